// Round 4
// baseline (586.092 us; speedup 1.0000x reference)
//
#include <hip/hip_runtime.h>
#include <hip/hip_bf16.h>

#define B_ 32
#define S_ 512
#define H_ 768
#define NH_ 12
#define DH_ 64
#define EC_ 4
#define CAPN_ 8

using short8  = __attribute__((ext_vector_type(8))) short;
using floatx4 = __attribute__((ext_vector_type(4))) float;
using uint2v  = __attribute__((ext_vector_type(2))) unsigned;
using bf16 = __hip_bfloat16;

#define VMCNT(n) asm volatile("s_waitcnt vmcnt(" #n ")" ::: "memory")

// async 16B global->LDS. LDS dest must be wave-uniform base + lane*16.
__device__ __forceinline__ void gl_lds16(const void* g, void* l) {
  __builtin_amdgcn_global_load_lds(
      (const __attribute__((address_space(1))) unsigned int*)g,
      (__attribute__((address_space(3))) unsigned int*)l, 16, 0, 0);
}

// pack two f32 -> one u32 of 2 bf16 (lo in low 16 bits)
__device__ __forceinline__ unsigned pk2(float lo, float hi) {
  __hip_bfloat162 h = __float22bfloat162_rn(make_float2(lo, hi));
  unsigned r;
  __builtin_memcpy(&r, &h, 4);
  return r;
}

// ---------- merged prep: blocks 0..767 = mean-partial + fp32->bf16 convert;
//            blocks 768..19199 = W[k][n] -> Wt[n][k] bf16 (4 mats x 8 experts) ----------
__global__ void k_prep(const float* __restrict__ X, bf16* __restrict__ Xh,
                       float* __restrict__ partial,
                       const float* __restrict__ Wq, const float* __restrict__ Wk,
                       const float* __restrict__ Wv, const float* __restrict__ Wo,
                       bf16* __restrict__ Wt) {
  __shared__ float tile[32][33];
  int f = blockIdx.x;
  if (f < 768) {
    int bx = f % 96, by = f / 96;
    int idx = bx * 256 + threadIdx.x;                // (b,h) 0..24575
    int b = idx / H_, h = idx - b * H_;
    int s0 = by * 64;
    size_t base = ((size_t)b * S_ + s0) * H_ + h;
    float sum = 0.f;
#pragma unroll 8
    for (int s = 0; s < 64; ++s) {
      float v = X[base + (size_t)s * H_];
      Xh[base + (size_t)s * H_] = __float2bfloat16(v);
      sum += v;
    }
    partial[(size_t)by * (B_ * H_) + idx] = sum;
  } else {
    int wid = f - 768;
    int z = wid / 576;
    int rem = wid - z * 576;
    int xx = rem / 24, yy = rem - xx * 24;
    const float* Wbase = (z < 8 ? Wq : z < 16 ? Wk : z < 24 ? Wv : Wo) + (size_t)(z & 7) * H_ * H_;
    int k0 = xx * 32, n0 = yy * 32;
    int tj = threadIdx.x & 31, ti = threadIdx.x >> 5; // ti 0..7
#pragma unroll
    for (int r = 0; r < 4; ++r)
      tile[ti + r * 8][tj] = Wbase[(size_t)(k0 + ti + r * 8) * H_ + n0 + tj];
    __syncthreads();
    bf16* out = Wt + (size_t)z * H_ * H_;
#pragma unroll
    for (int r = 0; r < 4; ++r)
      out[(size_t)(n0 + ti + r * 8) * H_ + k0 + tj] = __float2bfloat16(tile[tj][ti + r * 8]);
  }
}

// ---------- merged routing: reduce partials -> hmean (LDS) -> gate logits -> route ----------
__global__ __launch_bounds__(1024) void k_route_all(
    const float* __restrict__ partial,
    const float* __restrict__ Wsc, const float* __restrict__ bsc,
    const float* __restrict__ Wsu, const float* __restrict__ bsu,
    int* __restrict__ eidx) {
  __shared__ float hm[B_ * H_];                      // 98,304 B
  __shared__ float lg_s[B_ * 8];
  __shared__ float pcmax[B_];
  __shared__ int rc_s[B_], ru_s[B_];
  int t = threadIdx.x;
  // phase 1: reduce 8 partial chunks -> hmean in LDS
  for (int i = t; i < B_ * H_; i += 1024) {
    float s = 0.f;
#pragma unroll
    for (int c = 0; c < 8; ++c) s += partial[(size_t)c * (B_ * H_) + i];
    hm[i] = s * (1.f / 512.f);
  }
  __syncthreads();
  // phase 2: 256 gate logits (32 b x 8 gates), 4 threads each
  {
    int g = t >> 2, p = t & 3;
    int b = g >> 3, gi = g & 7;
    const float* w;
    float bias;
    if (gi < 4) { w = Wsc + gi; bias = bsc[gi]; }
    else        { w = Wsu + (gi - 4); bias = bsu[gi - 4]; }
    float acc = 0.f;
    for (int j = p; j < H_; j += 4) acc += hm[b * H_ + j] * w[j * 4];
    acc += __shfl_xor(acc, 1);
    acc += __shfl_xor(acc, 2);
    if (p == 0) lg_s[g] = acc + bias;
  }
  __syncthreads();
  // phase 3: per-b softmax max-prob + argmax
  if (t < B_) {
    float lg[8];
#pragma unroll
    for (int e = 0; e < 8; ++e) lg[e] = lg_s[t * 8 + e];
    float m = lg[0]; int a = 0;                      // first-max ties like jnp.argmax
    for (int e = 1; e < 4; ++e) if (lg[e] > m) { m = lg[e]; a = e; }
    float s = 0.f;
    for (int e = 0; e < 4; ++e) s += expf(lg[e] - m);
    pcmax[t] = 1.f / s;
    rc_s[t] = a;
    float mu = lg[4]; int au = 0;
    for (int e = 1; e < 4; ++e) if (lg[4 + e] > mu) { mu = lg[4 + e]; au = e; }
    ru_s[t] = au;
  }
  __syncthreads();
  // phase 4: serial capacity routing (stable descending selection == argsort(-p))
  if (t == 0) {
    bool used[B_], kept[B_];
    int cnt[EC_] = {0, 0, 0, 0};
    for (int i = 0; i < B_; ++i) used[i] = false;
    for (int i = 0; i < B_; ++i) {
      int best = 0; float bv = -1e30f;
      for (int j = 0; j < B_; ++j)
        if (!used[j] && pcmax[j] > bv) { bv = pcmax[j]; best = j; }
      used[best] = true;
      kept[best] = (++cnt[rc_s[best]] <= CAPN_);
    }
    for (int i = 0; i < B_; ++i)
      eidx[i] = kept[i] ? rc_s[i] : EC_ + ru_s[i];
  }
}

// ---------- GEMM: 128x128 tile, BK=64, 4 waves, mixed-depth counted-vmcnt ----------
// Y[m][n] = sum_k A[m][k]*Wt[n][k] + bias[n].  K=768 -> 12 K-tiles of 64.
// A: double-buffered (depth 1, latency covered by the compute phase);
// B: triple-buffered (depth 2).  LDS = 2x16 + 3x16 = 80 KB -> 2 blocks/CU.
// Per iter: stageA(kt+1), stageB(kt+2), compute(kt), VMCNT(4) [retires A(kt+1)
// and the older B(kt+1); only B(kt+2) stays in flight], ONE raw s_barrier.
// vmcnt never drains to 0 in the main loop; no implicit full drain anywhere.
// Chunk-XOR swizzle kc = pos ^ (row&7) on 128-B rows: measured 0 bank conflicts.
// 1D grid, XCD-chunked bijective decode; exact CU balance (2304 = 9x256, 768 = 3x256).
// OMODE 0: bf16 out (QKV; mat==2 writes V directly in Vt chunk layout)
// OMODE 1: fp32 out.  NM = mats per launch (3 QKV, 1 O) - compile-time.
template <int OMODE, int NM>
__global__ __launch_bounds__(256, 2) void k_gemm(
    const bf16* __restrict__ A, const bf16* __restrict__ Wt,
    const float* __restrict__ bias0, const float* __restrict__ bias1,
    const float* __restrict__ bias2,
    void* out0, void* out1, void* out2,
    const int* __restrict__ eidx, int mat0) {
  __shared__ __align__(16) char ldsA[2][16384];
  __shared__ __align__(16) char ldsB[3][16384];
  const int nwg = 96 * NM * 8;                       // 2304 or 768
  int wg = blockIdx.x;
  int f = (wg & 7) * (nwg >> 3) + (wg >> 3);         // XCD-chunked, bijective
  int b = f / (24 * NM);
  int r0 = f - b * 24 * NM;
  int mat = r0 / 24;
  int tile = r0 - mat * 24;
  int m0 = (tile & 3) * 128, n0 = (tile >> 2) * 128;
  int e = eidx[b];
  const bf16* Ab = A + (size_t)b * S_ * H_;
  const bf16* Wb = Wt + (size_t)((mat0 + mat) * 8 + e) * H_ * H_;
  const float* bias = ((mat == 0) ? bias0 : (mat == 1) ? bias1 : bias2) + (size_t)e * H_;
  void* outp = (mat == 0) ? out0 : (mat == 1) ? out1 : out2;

  int t = threadIdx.x, lane = t & 63, w = t >> 6;
  int wm = (w & 1) * 64, wn = (w >> 1) * 64;
  int lm = lane & 15, lq = lane >> 4;

  auto stageA = [&](char* buf, int kt) {
#pragma unroll
    for (int r = 0; r < 4; ++r) {                    // 1024 chunks of 16B
      int c = t + r * 256;
      int mm = c >> 3, pos = c & 7;
      int kc = pos ^ (mm & 7);                       // chunk-XOR swizzle (0-conflict)
      gl_lds16(Ab + (size_t)(m0 + mm) * H_ + kt * 64 + kc * 8, buf + (size_t)c * 16);
    }
  };
  auto stageB = [&](char* buf, int kt) {
#pragma unroll
    for (int r = 0; r < 4; ++r) {
      int c = t + r * 256;
      int nn = c >> 3, pos = c & 7;
      int kc = pos ^ (nn & 7);
      gl_lds16(Wb + (size_t)(n0 + nn) * H_ + kt * 64 + kc * 8, buf + (size_t)c * 16);
    }
  };

  floatx4 acc[4][4] = {};
  // prologue: A(0), B(0), B(1) in flight; wait for A(0)+B(0) (VMCNT leaves B(1))
  stageA(ldsA[0], 0);
  stageB(ldsB[0], 0);
  stageB(ldsB[1], 1);
  VMCNT(4);
  __builtin_amdgcn_s_barrier();
  __builtin_amdgcn_sched_barrier(0);

  int bcur = 0, bstage = 2;                          // B buffer of tile kt / kt+2
  for (int kt = 0; kt < 12; ++kt) {
    if (kt < 11) stageA(ldsA[(kt + 1) & 1], kt + 1);
    if (kt < 10) stageB(ldsB[bstage], kt + 2);
    const char* curA = ldsA[kt & 1];
    const char* curB = ldsB[bcur];
#pragma unroll
    for (int kf = 0; kf < 2; ++kf) {
      int kc = kf * 4 + lq;
      short8 af[4], bfr[4];
#pragma unroll
      for (int mf = 0; mf < 4; ++mf) {
        int mm = wm + mf * 16 + lm;
        af[mf] = *(const short8*)(curA + ((size_t)(mm * 8 + (kc ^ (mm & 7)))) * 16);
      }
#pragma unroll
      for (int nf = 0; nf < 4; ++nf) {
        int nn = wn + nf * 16 + lm;
        bfr[nf] = *(const short8*)(curB + ((size_t)(nn * 8 + (kc ^ (nn & 7)))) * 16);
      }
#pragma unroll
      for (int mf = 0; mf < 4; ++mf)
#pragma unroll
        for (int nf = 0; nf < 4; ++nf)
          acc[mf][nf] = __builtin_amdgcn_mfma_f32_16x16x32_bf16(af[mf], bfr[nf], acc[mf][nf], 0, 0, 0);
    }
    if (kt < 11) {
      // retire A(kt+1) + B(kt+1) (older); keep B(kt+2) in flight. Tail: full drain.
      if (kt < 10) { VMCNT(4); } else { VMCNT(0); }
      __builtin_amdgcn_s_barrier();                  // raw barrier: no implicit drain
      __builtin_amdgcn_sched_barrier(0);
    }
    ++bcur; if (bcur == 3) bcur = 0;
    ++bstage; if (bstage == 3) bstage = 0;
  }

  // epilogue: C/D layout col=lane&15, row=quad*4+reg
#pragma unroll
  for (int mf = 0; mf < 4; ++mf) {
#pragma unroll
    for (int nf = 0; nf < 4; ++nf) {
      int n = n0 + wn + nf * 16 + lm;
      float bv = bias[n];
      int mrow = m0 + wm + mf * 16 + lq * 4;
      size_t rowbase = ((size_t)b * S_ + mrow) * H_ + n;
#pragma unroll
      for (int r = 0; r < 4; ++r) {
        float v = acc[mf][nf][r] + bv;
        if (OMODE == 0) {
          if (mat == 2) {
            // V: write directly in Vt chunk layout [b*NH+h][s>>3][dh][s&7]
            int s = mrow + r;
            ((bf16*)outp)[((size_t)(b * NH_ + (n >> 6))) * 32768 +
                          (size_t)(s >> 3) * 512 + (n & 63) * 8 + (s & 7)] =
                __float2bfloat16(v);
          } else {
            ((bf16*)outp)[rowbase + (size_t)r * H_] = __float2bfloat16(v);
          }
        } else {
          ((float*)outp)[rowbase + (size_t)r * H_] = v;
        }
      }
    }
  }
}

// ---------- attention: barrier-free flash, fully in-register softmax ----------
// Block = 4 independent waves x 32 q-rows, one (b,h). Swapped-operand MFMAs:
//   S^T = mfma(K', Q)  with K rows permuted at load so that lane (lq,lm) ends up
//   holding S for q = mf*16+lm, k = {8lq..8lq+3}+4(nf&1)+32(nf>>1) -> the 16 P
//   values each lane needs are exactly its own PV B-frag elements (no LDS, no
//   cross-lane P movement; cvt_pk packs them in-register).
//   O^T = mfma(V^T, P^T): the Vt chunk layout already IS the V^T A-frag, and the
//   O^T accumulator's q-index is lane&15 == softmax state's q-index, so rescale
//   and 1/l need no transpose. Row-reduce = 15 lane-local ops + 2 shfl_xor.
__global__ __launch_bounds__(256, 3) void k_attn(
    const bf16* __restrict__ Q, const bf16* __restrict__ K,
    const bf16* __restrict__ Vt, const float* __restrict__ mask,
    bf16* __restrict__ Ctx) {
  int bh = blockIdx.x;
  int b = bh / NH_, h = bh - b * NH_;
  int t = threadIdx.x, lane = t & 63, w = t >> 6;
  int lm = lane & 15, lq = lane >> 4;
  int q0 = blockIdx.y * 128 + w * 32;                // this wave's 32 q-rows

  // Q B-frags (col=q=lm, k=kf*32+lq*8+e), one-shot from global
  short8 qf[2][2];
#pragma unroll
  for (int mf = 0; mf < 2; ++mf)
#pragma unroll
    for (int kf = 0; kf < 2; ++kf)
      qf[mf][kf] = *(const short8*)(Q + ((size_t)(b * S_ + q0 + mf * 16 + lm)) * H_ +
                                    h * DH_ + kf * 32 + lq * 8);

  // permuted K row for the A-frag: load row lm holds K row kr + koff[nf]
  int kr = ((lm >> 2) << 3) + (lm & 3);
  const int koff[4] = {0, 4, 32, 36};
  const bf16* kbase = K + ((size_t)(b * S_) + kr) * H_ + h * DH_ + lq * 8;
  const bf16* vtb = Vt + ((size_t)(b * NH_ + h)) * 32768;
  const float* mbase = mask + (size_t)b * S_ + lq * 8;

  floatx4 oacc[2][4] = {};                           // O^T: rows d=nf*16+4lq+r, col q=mf*16+lm
  float m_[2] = {-1e30f, -1e30f}, l_[2] = {0.f, 0.f};

  for (int kt = 0; kt < 8; ++kt) {
    // ---- S^T = K' Q : K A-frags straight from global (permuted rows) ----
    floatx4 sT[2][4] = {};
#pragma unroll
    for (int kf = 0; kf < 2; ++kf) {
      short8 kb4[4];
#pragma unroll
      for (int nf = 0; nf < 4; ++nf)
        kb4[nf] = *(const short8*)(kbase + (size_t)(kt * 64 + koff[nf]) * H_ + kf * 32);
#pragma unroll
      for (int mf = 0; mf < 2; ++mf)
#pragma unroll
        for (int nf = 0; nf < 4; ++nf)
          sT[mf][nf] = __builtin_amdgcn_mfma_f32_16x16x32_bf16(kb4[nf], qf[mf][kf], sT[mf][nf], 0, 0, 0);
    }
    // ---- V^T A-frags (issue early; latency hides under softmax VALU) ----
    short8 vf[2][4];
#pragma unroll
    for (int kf = 0; kf < 2; ++kf)
#pragma unroll
      for (int nf = 0; nf < 4; ++nf)
        vf[kf][nf] = *(const short8*)(vtb + (size_t)(kt * 8 + kf * 4 + lq) * 512 +
                                      (nf * 16 + lm) * 8);
    // ---- mask slots: k_rel = koff[nf] + 8*lq + r ----
    const floatx4* mp = (const floatx4*)(mbase + kt * 64);
    floatx4 mv[4] = {mp[0], mp[1], mp[8], mp[9]};

    // ---- lane-local online softmax (q = mf*16+lm; 16 k-slots per lane) ----
    short8 pf[2][2];
#pragma unroll
    for (int mf = 0; mf < 2; ++mf) {
      float p[4][4];
#pragma unroll
      for (int nf = 0; nf < 4; ++nf)
#pragma unroll
        for (int r = 0; r < 4; ++r)
          p[nf][r] = sT[mf][nf][r] * 0.125f + mv[nf][r];
      float t01 = fmaxf(fmaxf(fmaxf(p[0][0], p[0][1]), fmaxf(p[0][2], p[0][3])),
                        fmaxf(fmaxf(p[1][0], p[1][1]), fmaxf(p[1][2], p[1][3])));
      float t23 = fmaxf(fmaxf(fmaxf(p[2][0], p[2][1]), fmaxf(p[2][2], p[2][3])),
                        fmaxf(fmaxf(p[3][0], p[3][1]), fmaxf(p[3][2], p[3][3])));
      float tm = fmaxf(t01, t23);
      tm = fmaxf(tm, __shfl_xor(tm, 16));
      tm = fmaxf(tm, __shfl_xor(tm, 32));
      float mn = fmaxf(m_[mf], tm);
      float a = __expf(m_[mf] - mn);
      m_[mf] = mn;
      float ps = 0.f;
#pragma unroll
      for (int nf = 0; nf < 4; ++nf)
#pragma unroll
        for (int r = 0; r < 4; ++r) {
          p[nf][r] = __expf(p[nf][r] - mn);
          ps += p[nf][r];
        }
      ps += __shfl_xor(ps, 16);
      ps += __shfl_xor(ps, 32);
      l_[mf] = l_[mf] * a + ps;
#pragma unroll
      for (int nf = 0; nf < 4; ++nf) oacc[mf][nf] *= a;
      union { short8 s8; unsigned u[4]; } pku;
      pku.u[0] = pk2(p[0][0], p[0][1]); pku.u[1] = pk2(p[0][2], p[0][3]);
      pku.u[2] = pk2(p[1][0], p[1][1]); pku.u[3] = pk2(p[1][2], p[1][3]);
      pf[mf][0] = pku.s8;
      pku.u[0] = pk2(p[2][0], p[2][1]); pku.u[1] = pk2(p[2][2], p[2][3]);
      pku.u[2] = pk2(p[3][0], p[3][1]); pku.u[3] = pk2(p[3][2], p[3][3]);
      pf[mf][1] = pku.s8;
    }
    // ---- O^T += V^T P^T ----
#pragma unroll
    for (int kf = 0; kf < 2; ++kf)
#pragma unroll
      for (int mf = 0; mf < 2; ++mf)
#pragma unroll
        for (int nf = 0; nf < 4; ++nf)
          oacc[mf][nf] = __builtin_amdgcn_mfma_f32_16x16x32_bf16(vf[kf][nf], pf[mf][kf], oacc[mf][nf], 0, 0, 0);
  }
  // ---- epilogue: O^T rows d=nf*16+4lq+r, col q=mf*16+lm; 8B vector stores ----
#pragma unroll
  for (int mf = 0; mf < 2; ++mf) {
    float inv = 1.f / l_[mf];
    bf16* op = Ctx + ((size_t)(b * S_ + q0 + mf * 16 + lm)) * H_ + h * DH_ + lq * 4;
#pragma unroll
    for (int nf = 0; nf < 4; ++nf) {
      uint2v o;
      o.x = pk2(oacc[mf][nf][0] * inv, oacc[mf][nf][1] * inv);
      o.y = pk2(oacc[mf][nf][2] * inv, oacc[mf][nf][3] * inv);
      *(uint2v*)(op + nf * 16) = o;
    }
  }
}

extern "C" void kernel_launch(void* const* d_in, const int* in_sizes, int n_in,
                              void* d_out, int out_size, void* d_ws, size_t ws_size,
                              hipStream_t stream) {
  const float* X    = (const float*)d_in[0];
  const float* mask = (const float*)d_in[1];
  const float* Wq   = (const float*)d_in[2];
  const float* bq   = (const float*)d_in[3];
  const float* Wk   = (const float*)d_in[4];
  const float* bk   = (const float*)d_in[5];
  const float* Wv   = (const float*)d_in[6];
  const float* bv   = (const float*)d_in[7];
  const float* Wo   = (const float*)d_in[8];
  const float* bo   = (const float*)d_in[9];
  const float* Wsc  = (const float*)d_in[10];
  const float* bsc  = (const float*)d_in[11];
  const float* Wsu  = (const float*)d_in[12];
  const float* bsu  = (const float*)d_in[13];

  char* ws = (char*)d_ws;
  int*   eidx    = (int*)ws;                        //       128 B @ 0
  float* partial = (float*)(ws + 1280);             //   786,432 B
  bf16*  Xh      = (bf16*)(ws + 886016);            // 25,165,824 B
  bf16*  Wt      = (bf16*)(ws + 26051840);          // 37,748,736 B
  bf16*  qb      = (bf16*)(ws + 63800576);          // 25,165,824 B
  bf16*  kb      = (bf16*)(ws + 88966400);          // 25,165,824 B
  bf16*  Vt      = (bf16*)(ws + 114132224);         // 25,165,824 B -> 139,298,048 total
  bf16*  ctx     = Xh;                              // alias: Xh dead after QKV GEMM

  // 768 mean/convert blocks + 18432 transpose blocks, one launch
  k_prep<<<dim3(19200), 256, 0, stream>>>(X, Xh, partial, Wq, Wk, Wv, Wo, Wt);
  // reduce + gate + route fused into one block (hmean/logits live in LDS)
  k_route_all<<<dim3(1), 1024, 0, stream>>>(partial, Wsc, bsc, Wsu, bsu, eidx);
  // QKV: 32 b x 3 mats x 24 tiles = 2304 blocks = 9 x 256 CUs (exact balance)
  k_gemm<0, 3><<<dim3(2304), 256, 0, stream>>>(Xh, Wt, bq, bk, bv,
                                               (void*)qb, (void*)kb, (void*)Vt, eidx, 0);
  k_attn<<<dim3(B_ * NH_, 4), 256, 0, stream>>>(qb, kb, Vt, mask, ctx);
  // O: 32 b x 24 tiles = 768 blocks = 3 x 256 CUs (exact balance)
  k_gemm<1, 1><<<dim3(768), 256, 0, stream>>>(ctx, Wt, bo, bo, bo,
                                              d_out, d_out, d_out, eidx, 3);
}

// Round 5
// 452.899 us; speedup vs baseline: 1.2941x; 1.2941x over previous
//
#include <hip/hip_runtime.h>
#include <hip/hip_bf16.h>

#define B_ 32
#define S_ 512
#define H_ 768
#define NH_ 12
#define DH_ 64
#define EC_ 4
#define CAPN_ 8

using short8  = __attribute__((ext_vector_type(8))) short;
using floatx4 = __attribute__((ext_vector_type(4))) float;
using uint2v  = __attribute__((ext_vector_type(2))) unsigned;
using bf16 = __hip_bfloat16;

#define VMCNT(n) asm volatile("s_waitcnt vmcnt(" #n ")" ::: "memory")

// async 16B global->LDS. LDS dest must be wave-uniform base + lane*16.
__device__ __forceinline__ void gl_lds16(const void* g, void* l) {
  __builtin_amdgcn_global_load_lds(
      (const __attribute__((address_space(1))) unsigned int*)g,
      (__attribute__((address_space(3))) unsigned int*)l, 16, 0, 0);
}

// pack two f32 -> one u32 of 2 bf16 (lo in low 16 bits)
__device__ __forceinline__ unsigned pk2(float lo, float hi) {
  __hip_bfloat162 h = __float22bfloat162_rn(make_float2(lo, hi));
  unsigned r;
  __builtin_memcpy(&r, &h, 4);
  return r;
}

// ---------- merged prep: blocks 0..767 = mean-partial + fp32->bf16 convert;
//            blocks 768..19199 = W[k][n] -> Wt[n][k] bf16 (4 mats x 8 experts) ----------
__global__ void k_prep(const float* __restrict__ X, bf16* __restrict__ Xh,
                       float* __restrict__ partial,
                       const float* __restrict__ Wq, const float* __restrict__ Wk,
                       const float* __restrict__ Wv, const float* __restrict__ Wo,
                       bf16* __restrict__ Wt) {
  __shared__ float tile[32][33];
  int f = blockIdx.x;
  if (f < 768) {
    int bx = f % 96, by = f / 96;
    int idx = bx * 256 + threadIdx.x;                // (b,h) 0..24575
    int b = idx / H_, h = idx - b * H_;
    int s0 = by * 64;
    size_t base = ((size_t)b * S_ + s0) * H_ + h;
    float sum = 0.f;
#pragma unroll 8
    for (int s = 0; s < 64; ++s) {
      float v = X[base + (size_t)s * H_];
      Xh[base + (size_t)s * H_] = __float2bfloat16(v);
      sum += v;
    }
    partial[(size_t)by * (B_ * H_) + idx] = sum;
  } else {
    int wid = f - 768;
    int z = wid / 576;
    int rem = wid - z * 576;
    int xx = rem / 24, yy = rem - xx * 24;
    const float* Wbase = (z < 8 ? Wq : z < 16 ? Wk : z < 24 ? Wv : Wo) + (size_t)(z & 7) * H_ * H_;
    int k0 = xx * 32, n0 = yy * 32;
    int tj = threadIdx.x & 31, ti = threadIdx.x >> 5; // ti 0..7
#pragma unroll
    for (int r = 0; r < 4; ++r)
      tile[ti + r * 8][tj] = Wbase[(size_t)(k0 + ti + r * 8) * H_ + n0 + tj];
    __syncthreads();
    bf16* out = Wt + (size_t)z * H_ * H_;
#pragma unroll
    for (int r = 0; r < 4; ++r)
      out[(size_t)(n0 + ti + r * 8) * H_ + k0 + tj] = __float2bfloat16(tile[tj][ti + r * 8]);
  }
}

// ---------- routing: split small kernels (machine-wide, latency-friendly) ----------
__global__ void k_mean_reduce(const float* __restrict__ partial, float* __restrict__ hmean) {
  int idx = blockIdx.x * 256 + threadIdx.x;
  float s = 0.f;
#pragma unroll
  for (int c = 0; c < 8; ++c) s += partial[(size_t)c * (B_ * H_) + idx];
  hmean[idx] = s * (1.f / 512.f);                    // 1/512 exact
}

__global__ void k_gate(const float* __restrict__ hmean,
                       const float* __restrict__ Wsc, const float* __restrict__ bsc,
                       const float* __restrict__ Wsu, const float* __restrict__ bsu,
                       float* __restrict__ logits) {
  int b = blockIdx.x;
  int t = threadIdx.x;                               // 64 = 8 gates x 8 partials
  int g = t >> 3, p = t & 7;
  const float* hm = hmean + (size_t)b * H_;
  const float* w;
  float bias;
  if (g < 4) { w = Wsc + g; bias = bsc[g]; }
  else       { w = Wsu + (g - 4); bias = bsu[g - 4]; }
  float acc = 0.f;
  for (int j = p; j < H_; j += 8) acc += hm[j] * w[j * 4];
  acc += __shfl_xor(acc, 1);
  acc += __shfl_xor(acc, 2);
  acc += __shfl_xor(acc, 4);
  if (p == 0) logits[b * 8 + g] = acc + bias;
}

__global__ void k_route2(const float* __restrict__ logits, int* __restrict__ eidx) {
  __shared__ float pcmax[B_];
  __shared__ int rc_s[B_], ru_s[B_];
  int t = threadIdx.x;
  if (t < B_) {
    float lg[8];
#pragma unroll
    for (int e = 0; e < 8; ++e) lg[e] = logits[t * 8 + e];
    float m = lg[0]; int a = 0;                      // first-max ties like jnp.argmax
    for (int e = 1; e < 4; ++e) if (lg[e] > m) { m = lg[e]; a = e; }
    float s = 0.f;
    for (int e = 0; e < 4; ++e) s += expf(lg[e] - m);
    pcmax[t] = 1.f / s;                              // softmax max prob
    rc_s[t] = a;
    float mu = lg[4]; int au = 0;
    for (int e = 1; e < 4; ++e) if (lg[4 + e] > mu) { mu = lg[4 + e]; au = e; }
    ru_s[t] = au;
  }
  __syncthreads();
  if (t == 0) {
    // stable descending selection (equal -> lower index first) == argsort(-p)
    bool used[B_], kept[B_];
    int cnt[EC_] = {0, 0, 0, 0};
    for (int i = 0; i < B_; ++i) used[i] = false;
    for (int i = 0; i < B_; ++i) {
      int best = 0; float bv = -1e30f;
      for (int j = 0; j < B_; ++j)
        if (!used[j] && pcmax[j] > bv) { bv = pcmax[j]; best = j; }
      used[best] = true;
      kept[best] = (++cnt[rc_s[best]] <= CAPN_);
    }
    for (int i = 0; i < B_; ++i)
      eidx[i] = kept[i] ? rc_s[i] : EC_ + ru_s[i];
  }
}

// ---------- GEMM: 128x128 tile, BK=64, 4 waves, mixed-depth counted-vmcnt ----------
// Y[m][n] = sum_k A[m][k]*Wt[n][k] + bias[n].  K=768 -> 12 K-tiles of 64.
// A: double-buffered (depth 1, latency covered by the compute phase);
// B: triple-buffered (depth 2).  LDS = 2x16 + 3x16 = 80 KB -> 2 blocks/CU.
// Per iter: stageA(kt+1), stageB(kt+2), compute(kt), VMCNT(4) [retires A(kt+1)
// and the older B(kt+1); only B(kt+2) stays in flight], ONE raw s_barrier.
// vmcnt never drains to 0 in the main loop; no implicit full drain anywhere.
// Chunk-XOR swizzle kc = pos ^ (row&7) on 128-B rows: measured 0 bank conflicts.
// 1D grid, XCD-chunked bijective decode; exact CU balance (2304 = 9x256, 768 = 3x256).
// OMODE 0: bf16 out (QKV; mat==2 writes V directly in Vt chunk layout)
// OMODE 1: fp32 out.  NM = mats per launch (3 QKV, 1 O) - compile-time.
template <int OMODE, int NM>
__global__ __launch_bounds__(256, 2) void k_gemm(
    const bf16* __restrict__ A, const bf16* __restrict__ Wt,
    const float* __restrict__ bias0, const float* __restrict__ bias1,
    const float* __restrict__ bias2,
    void* out0, void* out1, void* out2,
    const int* __restrict__ eidx, int mat0) {
  __shared__ __align__(16) char ldsA[2][16384];
  __shared__ __align__(16) char ldsB[3][16384];
  const int nwg = 96 * NM * 8;                       // 2304 or 768
  int wg = blockIdx.x;
  int f = (wg & 7) * (nwg >> 3) + (wg >> 3);         // XCD-chunked, bijective
  int b = f / (24 * NM);
  int r0 = f - b * 24 * NM;
  int mat = r0 / 24;
  int tile = r0 - mat * 24;
  int m0 = (tile & 3) * 128, n0 = (tile >> 2) * 128;
  int e = eidx[b];
  const bf16* Ab = A + (size_t)b * S_ * H_;
  const bf16* Wb = Wt + (size_t)((mat0 + mat) * 8 + e) * H_ * H_;
  const float* bias = ((mat == 0) ? bias0 : (mat == 1) ? bias1 : bias2) + (size_t)e * H_;
  void* outp = (mat == 0) ? out0 : (mat == 1) ? out1 : out2;

  int t = threadIdx.x, lane = t & 63, w = t >> 6;
  int wm = (w & 1) * 64, wn = (w >> 1) * 64;
  int lm = lane & 15, lq = lane >> 4;

  auto stageA = [&](char* buf, int kt) {
#pragma unroll
    for (int r = 0; r < 4; ++r) {                    // 1024 chunks of 16B
      int c = t + r * 256;
      int mm = c >> 3, pos = c & 7;
      int kc = pos ^ (mm & 7);                       // chunk-XOR swizzle (0-conflict)
      gl_lds16(Ab + (size_t)(m0 + mm) * H_ + kt * 64 + kc * 8, buf + (size_t)c * 16);
    }
  };
  auto stageB = [&](char* buf, int kt) {
#pragma unroll
    for (int r = 0; r < 4; ++r) {
      int c = t + r * 256;
      int nn = c >> 3, pos = c & 7;
      int kc = pos ^ (nn & 7);
      gl_lds16(Wb + (size_t)(n0 + nn) * H_ + kt * 64 + kc * 8, buf + (size_t)c * 16);
    }
  };

  floatx4 acc[4][4] = {};
  // prologue: A(0), B(0), B(1) in flight; wait for A(0)+B(0) (VMCNT leaves B(1))
  stageA(ldsA[0], 0);
  stageB(ldsB[0], 0);
  stageB(ldsB[1], 1);
  VMCNT(4);
  __builtin_amdgcn_s_barrier();
  __builtin_amdgcn_sched_barrier(0);

  int bcur = 0, bstage = 2;                          // B buffer of tile kt / kt+2
  for (int kt = 0; kt < 12; ++kt) {
    if (kt < 11) stageA(ldsA[(kt + 1) & 1], kt + 1);
    if (kt < 10) stageB(ldsB[bstage], kt + 2);
    const char* curA = ldsA[kt & 1];
    const char* curB = ldsB[bcur];
#pragma unroll
    for (int kf = 0; kf < 2; ++kf) {
      int kc = kf * 4 + lq;
      short8 af[4], bfr[4];
#pragma unroll
      for (int mf = 0; mf < 4; ++mf) {
        int mm = wm + mf * 16 + lm;
        af[mf] = *(const short8*)(curA + ((size_t)(mm * 8 + (kc ^ (mm & 7)))) * 16);
      }
#pragma unroll
      for (int nf = 0; nf < 4; ++nf) {
        int nn = wn + nf * 16 + lm;
        bfr[nf] = *(const short8*)(curB + ((size_t)(nn * 8 + (kc ^ (nn & 7)))) * 16);
      }
#pragma unroll
      for (int mf = 0; mf < 4; ++mf)
#pragma unroll
        for (int nf = 0; nf < 4; ++nf)
          acc[mf][nf] = __builtin_amdgcn_mfma_f32_16x16x32_bf16(af[mf], bfr[nf], acc[mf][nf], 0, 0, 0);
    }
    if (kt < 11) {
      // retire A(kt+1) + B(kt+1) (older); keep B(kt+2) in flight. Tail: full drain.
      if (kt < 10) { VMCNT(4); } else { VMCNT(0); }
      __builtin_amdgcn_s_barrier();                  // raw barrier: no implicit drain
      __builtin_amdgcn_sched_barrier(0);
    }
    ++bcur; if (bcur == 3) bcur = 0;
    ++bstage; if (bstage == 3) bstage = 0;
  }

  // epilogue: C/D layout col=lane&15, row=quad*4+reg
#pragma unroll
  for (int mf = 0; mf < 4; ++mf) {
#pragma unroll
    for (int nf = 0; nf < 4; ++nf) {
      int n = n0 + wn + nf * 16 + lm;
      float bv = bias[n];
      int mrow = m0 + wm + mf * 16 + lq * 4;
      size_t rowbase = ((size_t)b * S_ + mrow) * H_ + n;
#pragma unroll
      for (int r = 0; r < 4; ++r) {
        float v = acc[mf][nf][r] + bv;
        if (OMODE == 0) {
          if (mat == 2) {
            // V: write directly in Vt chunk layout [b*NH+h][s>>3][dh][s&7]
            int s = mrow + r;
            ((bf16*)outp)[((size_t)(b * NH_ + (n >> 6))) * 32768 +
                          (size_t)(s >> 3) * 512 + (n & 63) * 8 + (s & 7)] =
                __float2bfloat16(v);
          } else {
            ((bf16*)outp)[rowbase + (size_t)r * H_] = __float2bfloat16(v);
          }
        } else {
          ((float*)outp)[rowbase + (size_t)r * H_] = v;
        }
      }
    }
  }
}

// ---------- attention: barrier-free flash, fully in-register softmax ----------
// Block = 4 independent waves x 32 q-rows, one (b,h). Swapped-operand MFMAs:
//   S^T = mfma(K', Q)  with K rows permuted at load so that lane (lq,lm) ends up
//   holding S for q = mf*16+lm, k = {8lq..8lq+3}+4(nf&1)+32(nf>>1) -> the 16 P
//   values each lane needs are exactly its own PV B-frag elements (no LDS, no
//   cross-lane P movement; cvt_pk packs them in-register).
//   O^T = mfma(V^T, P^T): the Vt chunk layout already IS the V^T A-frag, and the
//   O^T accumulator's q-index is lane&15 == softmax state's q-index, so rescale
//   and 1/l need no transpose. Row-reduce = 15 lane-local ops + 2 shfl_xor.
__global__ __launch_bounds__(256, 3) void k_attn(
    const bf16* __restrict__ Q, const bf16* __restrict__ K,
    const bf16* __restrict__ Vt, const float* __restrict__ mask,
    bf16* __restrict__ Ctx) {
  int bh = blockIdx.x;
  int b = bh / NH_, h = bh - b * NH_;
  int t = threadIdx.x, lane = t & 63, w = t >> 6;
  int lm = lane & 15, lq = lane >> 4;
  int q0 = blockIdx.y * 128 + w * 32;                // this wave's 32 q-rows

  // Q B-frags (col=q=lm, k=kf*32+lq*8+e), one-shot from global
  short8 qf[2][2];
#pragma unroll
  for (int mf = 0; mf < 2; ++mf)
#pragma unroll
    for (int kf = 0; kf < 2; ++kf)
      qf[mf][kf] = *(const short8*)(Q + ((size_t)(b * S_ + q0 + mf * 16 + lm)) * H_ +
                                    h * DH_ + kf * 32 + lq * 8);

  // permuted K row for the A-frag: load row lm holds K row kr + koff[nf]
  int kr = ((lm >> 2) << 3) + (lm & 3);
  const int koff[4] = {0, 4, 32, 36};
  const bf16* kbase = K + ((size_t)(b * S_) + kr) * H_ + h * DH_ + lq * 8;
  const bf16* vtb = Vt + ((size_t)(b * NH_ + h)) * 32768;
  const float* mbase = mask + (size_t)b * S_ + lq * 8;

  floatx4 oacc[2][4] = {};                           // O^T: rows d=nf*16+4lq+r, col q=mf*16+lm
  float m_[2] = {-1e30f, -1e30f}, l_[2] = {0.f, 0.f};

  for (int kt = 0; kt < 8; ++kt) {
    // ---- S^T = K' Q : K A-frags straight from global (permuted rows) ----
    floatx4 sT[2][4] = {};
#pragma unroll
    for (int kf = 0; kf < 2; ++kf) {
      short8 kb4[4];
#pragma unroll
      for (int nf = 0; nf < 4; ++nf)
        kb4[nf] = *(const short8*)(kbase + (size_t)(kt * 64 + koff[nf]) * H_ + kf * 32);
#pragma unroll
      for (int mf = 0; mf < 2; ++mf)
#pragma unroll
        for (int nf = 0; nf < 4; ++nf)
          sT[mf][nf] = __builtin_amdgcn_mfma_f32_16x16x32_bf16(kb4[nf], qf[mf][kf], sT[mf][nf], 0, 0, 0);
    }
    // ---- V^T A-frags (issue early; latency hides under softmax VALU) ----
    short8 vf[2][4];
#pragma unroll
    for (int kf = 0; kf < 2; ++kf)
#pragma unroll
      for (int nf = 0; nf < 4; ++nf)
        vf[kf][nf] = *(const short8*)(vtb + (size_t)(kt * 8 + kf * 4 + lq) * 512 +
                                      (nf * 16 + lm) * 8);
    // ---- mask slots: k_rel = koff[nf] + 8*lq + r ----
    const floatx4* mp = (const floatx4*)(mbase + kt * 64);
    floatx4 mv[4] = {mp[0], mp[1], mp[8], mp[9]};

    // ---- lane-local online softmax (q = mf*16+lm; 16 k-slots per lane) ----
    short8 pf[2][2];
#pragma unroll
    for (int mf = 0; mf < 2; ++mf) {
      float p[4][4];
#pragma unroll
      for (int nf = 0; nf < 4; ++nf)
#pragma unroll
        for (int r = 0; r < 4; ++r)
          p[nf][r] = sT[mf][nf][r] * 0.125f + mv[nf][r];
      float t01 = fmaxf(fmaxf(fmaxf(p[0][0], p[0][1]), fmaxf(p[0][2], p[0][3])),
                        fmaxf(fmaxf(p[1][0], p[1][1]), fmaxf(p[1][2], p[1][3])));
      float t23 = fmaxf(fmaxf(fmaxf(p[2][0], p[2][1]), fmaxf(p[2][2], p[2][3])),
                        fmaxf(fmaxf(p[3][0], p[3][1]), fmaxf(p[3][2], p[3][3])));
      float tm = fmaxf(t01, t23);
      tm = fmaxf(tm, __shfl_xor(tm, 16));
      tm = fmaxf(tm, __shfl_xor(tm, 32));
      float mn = fmaxf(m_[mf], tm);
      float a = __expf(m_[mf] - mn);
      m_[mf] = mn;
      float ps = 0.f;
#pragma unroll
      for (int nf = 0; nf < 4; ++nf)
#pragma unroll
        for (int r = 0; r < 4; ++r) {
          p[nf][r] = __expf(p[nf][r] - mn);
          ps += p[nf][r];
        }
      ps += __shfl_xor(ps, 16);
      ps += __shfl_xor(ps, 32);
      l_[mf] = l_[mf] * a + ps;
#pragma unroll
      for (int nf = 0; nf < 4; ++nf) oacc[mf][nf] *= a;
      union { short8 s8; unsigned u[4]; } pku;
      pku.u[0] = pk2(p[0][0], p[0][1]); pku.u[1] = pk2(p[0][2], p[0][3]);
      pku.u[2] = pk2(p[1][0], p[1][1]); pku.u[3] = pk2(p[1][2], p[1][3]);
      pf[mf][0] = pku.s8;
      pku.u[0] = pk2(p[2][0], p[2][1]); pku.u[1] = pk2(p[2][2], p[2][3]);
      pku.u[2] = pk2(p[3][0], p[3][1]); pku.u[3] = pk2(p[3][2], p[3][3]);
      pf[mf][1] = pku.s8;
    }
    // ---- O^T += V^T P^T ----
#pragma unroll
    for (int kf = 0; kf < 2; ++kf)
#pragma unroll
      for (int mf = 0; mf < 2; ++mf)
#pragma unroll
        for (int nf = 0; nf < 4; ++nf)
          oacc[mf][nf] = __builtin_amdgcn_mfma_f32_16x16x32_bf16(vf[kf][nf], pf[mf][kf], oacc[mf][nf], 0, 0, 0);
  }
  // ---- epilogue: O^T rows d=nf*16+4lq+r, col q=mf*16+lm; 8B vector stores ----
#pragma unroll
  for (int mf = 0; mf < 2; ++mf) {
    float inv = 1.f / l_[mf];
    bf16* op = Ctx + ((size_t)(b * S_ + q0 + mf * 16 + lm)) * H_ + h * DH_ + lq * 4;
#pragma unroll
    for (int nf = 0; nf < 4; ++nf) {
      uint2v o;
      o.x = pk2(oacc[mf][nf][0] * inv, oacc[mf][nf][1] * inv);
      o.y = pk2(oacc[mf][nf][2] * inv, oacc[mf][nf][3] * inv);
      *(uint2v*)(op + nf * 16) = o;
    }
  }
}

extern "C" void kernel_launch(void* const* d_in, const int* in_sizes, int n_in,
                              void* d_out, int out_size, void* d_ws, size_t ws_size,
                              hipStream_t stream) {
  const float* X    = (const float*)d_in[0];
  const float* mask = (const float*)d_in[1];
  const float* Wq   = (const float*)d_in[2];
  const float* bq   = (const float*)d_in[3];
  const float* Wk   = (const float*)d_in[4];
  const float* bk   = (const float*)d_in[5];
  const float* Wv   = (const float*)d_in[6];
  const float* bv   = (const float*)d_in[7];
  const float* Wo   = (const float*)d_in[8];
  const float* bo   = (const float*)d_in[9];
  const float* Wsc  = (const float*)d_in[10];
  const float* bsc  = (const float*)d_in[11];
  const float* Wsu  = (const float*)d_in[12];
  const float* bsu  = (const float*)d_in[13];

  char* ws = (char*)d_ws;
  int*   eidx    = (int*)ws;                        //       128 B @ 0
  float* logits  = (float*)(ws + 128);              //     1,024 B
  float* partial = (float*)(ws + 1280);             //   786,432 B
  float* hmean   = (float*)(ws + 787712);           //    98,304 B
  bf16*  Xh      = (bf16*)(ws + 886016);            // 25,165,824 B
  bf16*  Wt      = (bf16*)(ws + 26051840);          // 37,748,736 B
  bf16*  qb      = (bf16*)(ws + 63800576);          // 25,165,824 B
  bf16*  kb      = (bf16*)(ws + 88966400);          // 25,165,824 B
  bf16*  Vt      = (bf16*)(ws + 114132224);         // 25,165,824 B -> 139,298,048 total
  bf16*  ctx     = Xh;                              // alias: Xh dead after QKV GEMM

  // 768 mean/convert blocks + 18432 transpose blocks, one launch
  k_prep<<<dim3(19200), 256, 0, stream>>>(X, Xh, partial, Wq, Wk, Wv, Wo, Wt);
  // routing: split small kernels (machine-wide; the 1-block fusion was 231 us)
  k_mean_reduce<<<96, 256, 0, stream>>>(partial, hmean);
  k_gate<<<B_, 64, 0, stream>>>(hmean, Wsc, bsc, Wsu, bsu, logits);
  k_route2<<<1, 64, 0, stream>>>(logits, eidx);
  // QKV: 32 b x 3 mats x 24 tiles = 2304 blocks = 9 x 256 CUs (exact balance)
  k_gemm<0, 3><<<dim3(2304), 256, 0, stream>>>(Xh, Wt, bq, bk, bv,
                                               (void*)qb, (void*)kb, (void*)Vt, eidx, 0);
  k_attn<<<dim3(B_ * NH_, 4), 256, 0, stream>>>(qb, kb, Vt, mask, ctx);
  // O: 32 b x 24 tiles = 768 blocks = 3 x 256 CUs (exact balance)
  k_gemm<1, 1><<<dim3(768), 256, 0, stream>>>(ctx, Wt, bo, bo, bo,
                                              d_out, d_out, d_out, eidx, 3);
}